// Round 2
// baseline (772.638 us; speedup 1.0000x reference)
//
#include <hip/hip_runtime.h>
#include <hip/hip_bf16.h>

#define NFEAT 128
#define HID 256
#define BN_EPS 1e-5f

typedef __attribute__((ext_vector_type(8))) __bf16 bf16x8;
typedef __attribute__((ext_vector_type(4))) float f32x4;

static __device__ __forceinline__ float bf2f(__hip_bfloat16 v) { return __bfloat162float(v); }

// ---------- CSR build ----------
__global__ void k_count(const int* __restrict__ ei, int E, int* __restrict__ cnt) {
    int e = blockIdx.x * blockDim.x + threadIdx.x;
    if (e < E) atomicAdd(&cnt[ei[E + e]], 1);
}

__global__ void k_scan1(const int* __restrict__ cnt, int n, int* __restrict__ partial,
                        int* __restrict__ blk_total) {
    __shared__ int sh[256];
    int i = blockIdx.x * 256 + threadIdx.x;
    int v = (i < n) ? cnt[i] : 0;
    sh[threadIdx.x] = v;
    __syncthreads();
    for (int off = 1; off < 256; off <<= 1) {
        int x = (threadIdx.x >= off) ? sh[threadIdx.x - off] : 0;
        __syncthreads();
        sh[threadIdx.x] += x;
        __syncthreads();
    }
    if (i < n) partial[i] = sh[threadIdx.x] - v;  // exclusive within block
    if (threadIdx.x == 255) blk_total[blockIdx.x] = sh[255];
}

__global__ void k_scan2(int* __restrict__ blk, int nb) {
    __shared__ int sh[256];
    int t = threadIdx.x;
    int v = (t < nb) ? blk[t] : 0;
    sh[t] = v;
    __syncthreads();
    for (int off = 1; off < 256; off <<= 1) {
        int x = (t >= off) ? sh[t - off] : 0;
        __syncthreads();
        sh[t] += x;
        __syncthreads();
    }
    if (t < nb) blk[t] = sh[t] - v;  // exclusive block offsets, in place
}

__global__ void k_finalize(const int* __restrict__ partial, const int* __restrict__ blk,
                           const int* __restrict__ cnt, int n, int* __restrict__ row_start,
                           int* __restrict__ cursor, float* __restrict__ dinv) {
    int i = blockIdx.x * blockDim.x + threadIdx.x;
    if (i < n) {
        int s = partial[i] + blk[i >> 8];
        row_start[i] = s;
        cursor[i] = s;
        dinv[i] = rsqrtf((float)(cnt[i] + 1));  // deg = in-edges + self-loop, >= 1
    }
}

__global__ void k_fill(const int* __restrict__ ei, int E, int* __restrict__ cursor,
                       int* __restrict__ col) {
    int e = blockIdx.x * blockDim.x + threadIdx.x;
    if (e < E) {
        int d = ei[E + e];
        int pos = atomicAdd(&cursor[d], 1);
        col[pos] = ei[e];
    }
}

// ---------- fp32 -> bf16 cast ----------
__global__ void k_cast(const float* __restrict__ in, __hip_bfloat16* __restrict__ out, int n4) {
    int i = blockIdx.x * blockDim.x + threadIdx.x;
    if (i < n4) {
        float4 v = *(const float4*)(in + (size_t)i * 4);
        __hip_bfloat16* o = out + (size_t)i * 4;
        o[0] = __float2bfloat16(v.x);
        o[1] = __float2bfloat16(v.y);
        o[2] = __float2bfloat16(v.z);
        o[3] = __float2bfloat16(v.w);
    }
}

// ---------- weight transpose+cast (W[K][N] fp32 -> Wt[N][K] bf16) ----------
__global__ void k_transpose(const float* __restrict__ W, __hip_bfloat16* __restrict__ Wt, int K,
                            int Nc) {
    int idx = blockIdx.x * blockDim.x + threadIdx.x;
    if (idx < K * Nc) {
        int n = idx % Nc;
        int k = idx / Nc;
        Wt[n * K + k] = __float2bfloat16(W[k * Nc + n]);
    }
}

// ---------- bf16 MFMA GEMM: out[M][256] = A[M][K] @ B[K][256] ----------
// Bt is B transposed: Bt[256][K]. Tile 64x64, 256 threads = 4 waves,
// wave w computes rows [16w,16w+16) x 64 cols (4 MFMA tiles).
// LDS rows padded to 40 elems (80B): b128 reads 16B-aligned, <=2-way bank alias (free).
// Writes bf16 (outb) for intermediate layers, or fp32+bias (outf) for the final layer.
__global__ __launch_bounds__(256) void k_gemm(const __hip_bfloat16* __restrict__ A,
                                              const __hip_bfloat16* __restrict__ Bt,
                                              const float* __restrict__ bias,
                                              __hip_bfloat16* __restrict__ outb,
                                              float* __restrict__ outf, int M, int K) {
    __shared__ __align__(16) unsigned short As[64 * 40];
    __shared__ __align__(16) unsigned short Bs[64 * 40];
    const int t = threadIdx.x;
    const int wv = t >> 6;
    const int lane = t & 63;
    const int mlane = lane & 15;
    const int quad = lane >> 4;
    const int m0 = blockIdx.x * 64;
    const int n0 = blockIdx.y * 64;
    const int lr = t >> 2;       // load row 0..63
    const int lk = (t & 3) * 8;  // k offset 0,8,16,24
    const int arow = m0 + lr;

    f32x4 acc[4];
#pragma unroll
    for (int i = 0; i < 4; i++) acc[i] = (f32x4){0.f, 0.f, 0.f, 0.f};

    for (int k0 = 0; k0 < K; k0 += 32) {
        uint4 av = {0u, 0u, 0u, 0u};
        if (arow < M) av = *(const uint4*)(A + (size_t)arow * K + k0 + lk);
        *(uint4*)(As + lr * 40 + lk) = av;
        uint4 bv = *(const uint4*)(Bt + (size_t)(n0 + lr) * K + k0 + lk);
        *(uint4*)(Bs + lr * 40 + lk) = bv;
        __syncthreads();
        bf16x8 af = *(const bf16x8*)(As + (16 * wv + mlane) * 40 + quad * 8);
#pragma unroll
        for (int tt = 0; tt < 4; tt++) {
            bf16x8 bfr = *(const bf16x8*)(Bs + (16 * tt + mlane) * 40 + quad * 8);
            acc[tt] = __builtin_amdgcn_mfma_f32_16x16x32_bf16(af, bfr, acc[tt], 0, 0, 0);
        }
        __syncthreads();
    }
    // C/D mapping (verified): col = lane&15, row = quad*4 + reg
#pragma unroll
    for (int tt = 0; tt < 4; tt++) {
        int col = n0 + 16 * tt + mlane;
        float bv = bias ? bias[col] : 0.f;
#pragma unroll
        for (int r = 0; r < 4; r++) {
            int row = m0 + 16 * wv + quad * 4 + r;
            if (row < M) {
                if (outb)
                    outb[(size_t)row * HID + col] = __float2bfloat16(acc[tt][r]);
                else
                    outf[(size_t)row * HID + col] = acc[tt][r] + bv;
            }
        }
    }
}

// ---------- SpMM: out[i] = sum_{j->i} dinv_i dinv_j H[j] + dinv_i^2 H[i] + b ----------
__global__ __launch_bounds__(256) void k_spmm(const __hip_bfloat16* __restrict__ H,
                                              const int* __restrict__ rs,
                                              const int* __restrict__ rc,
                                              const int* __restrict__ col,
                                              const float* __restrict__ dinv,
                                              const float* __restrict__ bias,
                                              float* __restrict__ out) {
    const int r = blockIdx.x;
    const int t = threadIdx.x;
    const float di = dinv[r];
    float acc = di * di * bf2f(H[(size_t)r * HID + t]);  // self-loop
    const int s = rs[r];
    const int c = rc[r];
    for (int e = 0; e < c; e++) {
        int src = col[s + e];
        acc += di * dinv[src] * bf2f(H[(size_t)src * HID + t]);
    }
    out[(size_t)r * HID + t] = acc + bias[t];
}

// ---------- BatchNorm ----------
__global__ __launch_bounds__(256) void k_bnstats(const float* __restrict__ in, int n,
                                                 float* __restrict__ gsum,
                                                 float* __restrict__ gsq) {
    const int t = threadIdx.x;  // channel
    float s = 0.f, q = 0.f;
    for (int r = blockIdx.x; r < n; r += gridDim.x) {
        float v = in[(size_t)r * HID + t];
        s += v;
        q += v * v;
    }
    atomicAdd(&gsum[t], s);
    atomicAdd(&gsq[t], q);
}

__global__ __launch_bounds__(256) void k_bnnorm(const float* __restrict__ in,
                                                const float* __restrict__ gsum,
                                                const float* __restrict__ gsq,
                                                const float* __restrict__ g,
                                                const float* __restrict__ be, int n,
                                                __hip_bfloat16* __restrict__ out) {
    int idx = blockIdx.x * blockDim.x + threadIdx.x;
    if (idx < n * HID) {
        int c = idx & (HID - 1);
        float invn = 1.0f / (float)n;
        float mean = gsum[c] * invn;
        float var = gsq[c] * invn - mean * mean;
        float sc = rsqrtf(var + BN_EPS) * g[c];
        out[idx] = __float2bfloat16((in[idx] - mean) * sc + be[c]);
    }
}

extern "C" void kernel_launch(void* const* d_in, const int* in_sizes, int n_in, void* d_out,
                              int out_size, void* d_ws, size_t ws_size, hipStream_t stream) {
    const float* x = (const float*)d_in[0];
    const int* ei = (const int*)d_in[1];
    const float* W1 = (const float*)d_in[2];
    const float* b1 = (const float*)d_in[3];
    const float* g1 = (const float*)d_in[4];
    const float* be1 = (const float*)d_in[5];
    const float* W2 = (const float*)d_in[6];
    const float* b2 = (const float*)d_in[7];
    const float* g2 = (const float*)d_in[8];
    const float* be2 = (const float*)d_in[9];
    const float* Wfc = (const float*)d_in[10];
    const float* bfc = (const float*)d_in[11];
    float* out = (float*)d_out;

    const int N = in_sizes[0] / NFEAT;  // 50000
    const int E = in_sizes[1] / 2;      // 800000

    char* ws = (char*)d_ws;
    size_t off = 0;
    auto alloc = [&](size_t bytes) -> void* {
        void* p = ws + off;
        off += (bytes + 255) & ~(size_t)255;
        return p;
    };
    int* row_cnt = (int*)alloc((size_t)N * 4);
    int* partial = (int*)alloc((size_t)N * 4);
    int* row_start = (int*)alloc((size_t)N * 4);
    int* cursor = (int*)alloc((size_t)N * 4);
    int* blk = (int*)alloc(256 * 4);
    float* dinv = (float*)alloc((size_t)N * 4);
    int* col_idx = (int*)alloc((size_t)E * 4);
    float* gstats = (float*)alloc(512 * 4);
    __hip_bfloat16* Wt1 = (__hip_bfloat16*)alloc(256 * 128 * 2);
    __hip_bfloat16* Wt2 = (__hip_bfloat16*)alloc(256 * 256 * 2);
    __hip_bfloat16* Wtf = (__hip_bfloat16*)alloc(256 * 256 * 2);
    __hip_bfloat16* xb = (__hip_bfloat16*)alloc((size_t)N * NFEAT * 2);
    __hip_bfloat16* bufH = (__hip_bfloat16*)alloc((size_t)N * HID * 2);  // GEMM out (bf16)
    __hip_bfloat16* bufB = (__hip_bfloat16*)alloc((size_t)N * HID * 2);  // BN out (bf16)
    float* bufF = (float*)alloc((size_t)N * HID * 4);                    // SpMM out (fp32)

    // CSR build + degrees
    hipMemsetAsync(row_cnt, 0, (size_t)N * 4, stream);
    k_count<<<(E + 255) / 256, 256, 0, stream>>>(ei, E, row_cnt);
    int nblk = (N + 255) / 256;  // 196 (<=256 so single-block scan2 works)
    k_scan1<<<nblk, 256, 0, stream>>>(row_cnt, N, partial, blk);
    k_scan2<<<1, 256, 0, stream>>>(blk, nblk);
    k_finalize<<<nblk, 256, 0, stream>>>(partial, blk, row_cnt, N, row_start, cursor, dinv);
    k_fill<<<(E + 255) / 256, 256, 0, stream>>>(ei, E, cursor, col_idx);

    // casts: x -> bf16, weights -> transposed bf16
    k_cast<<<(N * NFEAT / 4 + 255) / 256, 256, 0, stream>>>(x, xb, N * NFEAT / 4);
    k_transpose<<<(128 * 256) / 256, 256, 0, stream>>>(W1, Wt1, 128, 256);
    k_transpose<<<(256 * 256) / 256, 256, 0, stream>>>(W2, Wt2, 256, 256);
    k_transpose<<<(256 * 256) / 256, 256, 0, stream>>>(Wfc, Wtf, 256, 256);

    dim3 gg((N + 63) / 64, 4);
    // Layer 1
    k_gemm<<<gg, 256, 0, stream>>>(xb, Wt1, nullptr, bufH, nullptr, N, NFEAT);
    k_spmm<<<N, 256, 0, stream>>>(bufH, row_start, row_cnt, col_idx, dinv, b1, bufF);
    hipMemsetAsync(gstats, 0, 512 * 4, stream);
    k_bnstats<<<256, 256, 0, stream>>>(bufF, N, gstats, gstats + 256);
    k_bnnorm<<<(N * HID + 255) / 256, 256, 0, stream>>>(bufF, gstats, gstats + 256, g1, be1, N,
                                                        bufB);
    // Layer 2
    k_gemm<<<gg, 256, 0, stream>>>(bufB, Wt2, nullptr, bufH, nullptr, N, HID);
    k_spmm<<<N, 256, 0, stream>>>(bufH, row_start, row_cnt, col_idx, dinv, b2, bufF);
    hipMemsetAsync(gstats, 0, 512 * 4, stream);
    k_bnstats<<<256, 256, 0, stream>>>(bufF, N, gstats, gstats + 256);
    k_bnnorm<<<(N * HID + 255) / 256, 256, 0, stream>>>(bufF, gstats, gstats + 256, g2, be2, N,
                                                        bufB);
    // Final linear (fp32 out + bias)
    k_gemm<<<gg, 256, 0, stream>>>(bufB, Wtf, bfc, nullptr, out, N, HID);
}

// Round 3
// 542.982 us; speedup vs baseline: 1.4230x; 1.4230x over previous
//
#include <hip/hip_runtime.h>
#include <hip/hip_bf16.h>

#define NFEAT 128
#define HID 256
#define BN_EPS 1e-5f

typedef __attribute__((ext_vector_type(8))) __bf16 bf16x8;
typedef __attribute__((ext_vector_type(4))) float f32x4;

static __device__ __forceinline__ float bflo(unsigned u) {
    union { unsigned x; float f; } c; c.x = u << 16; return c.f;
}
static __device__ __forceinline__ float bfhi(unsigned u) {
    union { unsigned x; float f; } c; c.x = u & 0xffff0000u; return c.f;
}

// ---------- CSR build ----------
__global__ void k_count(const int* __restrict__ ei, int E, int* __restrict__ cnt) {
    int e = blockIdx.x * blockDim.x + threadIdx.x;
    if (e < E) atomicAdd(&cnt[ei[E + e]], 1);
}

__global__ void k_scan1(const int* __restrict__ cnt, int n, int* __restrict__ partial,
                        int* __restrict__ blk_total) {
    __shared__ int sh[256];
    int i = blockIdx.x * 256 + threadIdx.x;
    int v = (i < n) ? cnt[i] : 0;
    sh[threadIdx.x] = v;
    __syncthreads();
    for (int off = 1; off < 256; off <<= 1) {
        int x = (threadIdx.x >= off) ? sh[threadIdx.x - off] : 0;
        __syncthreads();
        sh[threadIdx.x] += x;
        __syncthreads();
    }
    if (i < n) partial[i] = sh[threadIdx.x] - v;  // exclusive within block
    if (threadIdx.x == 255) blk_total[blockIdx.x] = sh[255];
}

__global__ void k_scan2(int* __restrict__ blk, int nb) {
    __shared__ int sh[256];
    int t = threadIdx.x;
    int v = (t < nb) ? blk[t] : 0;
    sh[t] = v;
    __syncthreads();
    for (int off = 1; off < 256; off <<= 1) {
        int x = (t >= off) ? sh[t - off] : 0;
        __syncthreads();
        sh[t] += x;
        __syncthreads();
    }
    if (t < nb) blk[t] = sh[t] - v;  // exclusive block offsets, in place
}

__global__ void k_finalize(const int* __restrict__ partial, const int* __restrict__ blk,
                           const int* __restrict__ cnt, int n, int* __restrict__ row_start,
                           int* __restrict__ cursor, float* __restrict__ dinv) {
    int i = blockIdx.x * blockDim.x + threadIdx.x;
    if (i < n) {
        int s = partial[i] + blk[i >> 8];
        row_start[i] = s;
        cursor[i] = s;
        dinv[i] = rsqrtf((float)(cnt[i] + 1));  // deg = in-edges + self-loop, >= 1
    }
}

__global__ void k_fill(const int* __restrict__ ei, int E, int* __restrict__ cursor,
                       int* __restrict__ col) {
    int e = blockIdx.x * blockDim.x + threadIdx.x;
    if (e < E) {
        int d = ei[E + e];
        int pos = atomicAdd(&cursor[d], 1);
        col[pos] = ei[e];
    }
}

// ---------- fp32 -> bf16 cast with per-row dinv scale ----------
__global__ void k_scale_cast(const float* __restrict__ in, const float* __restrict__ dinv,
                             __hip_bfloat16* __restrict__ out, int shift, int n4) {
    int i = blockIdx.x * blockDim.x + threadIdx.x;
    if (i < n4) {
        float d = dinv[i >> shift];  // shift = log2(C/4)
        float4 v = *(const float4*)(in + (size_t)i * 4);
        __hip_bfloat16* o = out + (size_t)i * 4;
        o[0] = __float2bfloat16(v.x * d);
        o[1] = __float2bfloat16(v.y * d);
        o[2] = __float2bfloat16(v.z * d);
        o[3] = __float2bfloat16(v.w * d);
    }
}

// ---------- weight transpose+cast (W[K][N] fp32 -> Wt[N][K] bf16) ----------
__global__ void k_transpose(const float* __restrict__ W, __hip_bfloat16* __restrict__ Wt, int K,
                            int Nc) {
    int idx = blockIdx.x * blockDim.x + threadIdx.x;
    if (idx < K * Nc) {
        int n = idx % Nc;
        int k = idx / Nc;
        Wt[n * K + k] = __float2bfloat16(W[k * Nc + n]);
    }
}

// ---------- SpMM on pre-scaled rows: out_i = dinv_i * (sum_{j->i} Hs_j + Hs_i) ----------
// Hs rows already scaled by dinv_j. Thread t owns 8 channels (one 16B load);
// EP = 256/(C/8) edges in flight per block; LDS combine at the end.
template <int C>
__global__ __launch_bounds__(256) void k_spmm(const __hip_bfloat16* __restrict__ Hs,
                                              const int* __restrict__ rs,
                                              const int* __restrict__ rc,
                                              const int* __restrict__ col,
                                              const float* __restrict__ dinv,
                                              __hip_bfloat16* __restrict__ out) {
    constexpr int G = C / 8;     // thread-groups per row slice
    constexpr int EP = 256 / G;  // edge parallelism
    __shared__ float red[EP][C];
    const int r = blockIdx.x;
    const int t = threadIdx.x;
    const int ch = (t & (G - 1)) * 8;
    const int es = t / G;
    const int s = rs[r];
    const int c = rc[r];

    float acc[8];
#pragma unroll
    for (int i = 0; i < 8; i++) acc[i] = 0.f;

    // self-loop handled by edge-slot 0
    if (es == 0) {
        uint4 v = *(const uint4*)(Hs + (size_t)r * C + ch);
        acc[0] = bflo(v.x); acc[1] = bfhi(v.x);
        acc[2] = bflo(v.y); acc[3] = bfhi(v.y);
        acc[4] = bflo(v.z); acc[5] = bfhi(v.z);
        acc[6] = bflo(v.w); acc[7] = bfhi(v.w);
    }
    for (int e = es; e < c; e += EP) {
        int src = col[s + e];
        uint4 v = *(const uint4*)(Hs + (size_t)src * C + ch);
        acc[0] += bflo(v.x); acc[1] += bfhi(v.x);
        acc[2] += bflo(v.y); acc[3] += bfhi(v.y);
        acc[4] += bflo(v.z); acc[5] += bfhi(v.z);
        acc[6] += bflo(v.w); acc[7] += bfhi(v.w);
    }
#pragma unroll
    for (int i = 0; i < 8; i++) red[es][ch + i] = acc[i];
    __syncthreads();
    if (t < C) {
        float tot = 0.f;
#pragma unroll
        for (int j = 0; j < EP; j++) tot += red[j][t];
        out[(size_t)r * C + t] = __float2bfloat16(dinv[r] * tot);
    }
}

// ---------- bf16 MFMA GEMM: out[M][256] = A[M][K] @ B[K][256] + bias (fp32 out) ----------
__global__ __launch_bounds__(256) void k_gemm(const __hip_bfloat16* __restrict__ A,
                                              const __hip_bfloat16* __restrict__ Bt,
                                              const float* __restrict__ bias,
                                              float* __restrict__ outf, int M, int K) {
    __shared__ __align__(16) unsigned short As[64 * 40];
    __shared__ __align__(16) unsigned short Bs[64 * 40];
    const int t = threadIdx.x;
    const int wv = t >> 6;
    const int lane = t & 63;
    const int mlane = lane & 15;
    const int quad = lane >> 4;
    const int m0 = blockIdx.x * 64;
    const int n0 = blockIdx.y * 64;
    const int lr = t >> 2;       // load row 0..63
    const int lk = (t & 3) * 8;  // k offset 0,8,16,24
    const int arow = m0 + lr;

    f32x4 acc[4];
#pragma unroll
    for (int i = 0; i < 4; i++) acc[i] = (f32x4){0.f, 0.f, 0.f, 0.f};

    for (int k0 = 0; k0 < K; k0 += 32) {
        uint4 av = {0u, 0u, 0u, 0u};
        if (arow < M) av = *(const uint4*)(A + (size_t)arow * K + k0 + lk);
        *(uint4*)(As + lr * 40 + lk) = av;
        uint4 bv = *(const uint4*)(Bt + (size_t)(n0 + lr) * K + k0 + lk);
        *(uint4*)(Bs + lr * 40 + lk) = bv;
        __syncthreads();
        bf16x8 af = *(const bf16x8*)(As + (16 * wv + mlane) * 40 + quad * 8);
#pragma unroll
        for (int tt = 0; tt < 4; tt++) {
            bf16x8 bfr = *(const bf16x8*)(Bs + (16 * tt + mlane) * 40 + quad * 8);
            acc[tt] = __builtin_amdgcn_mfma_f32_16x16x32_bf16(af, bfr, acc[tt], 0, 0, 0);
        }
        __syncthreads();
    }
    // C/D mapping (verified): col = lane&15, row = quad*4 + reg
#pragma unroll
    for (int tt = 0; tt < 4; tt++) {
        int colx = n0 + 16 * tt + mlane;
        float bv = bias[colx];
#pragma unroll
        for (int r = 0; r < 4; r++) {
            int row = m0 + 16 * wv + quad * 4 + r;
            if (row < M) outf[(size_t)row * HID + colx] = acc[tt][r] + bv;
        }
    }
}

// ---------- BatchNorm ----------
__global__ __launch_bounds__(256) void k_bnstats(const float* __restrict__ in, int n,
                                                 float* __restrict__ gsum,
                                                 float* __restrict__ gsq) {
    const int t = threadIdx.x;  // channel
    float s = 0.f, q = 0.f;
    for (int r = blockIdx.x; r < n; r += gridDim.x) {
        float v = in[(size_t)r * HID + t];
        s += v;
        q += v * v;
    }
    atomicAdd(&gsum[t], s);
    atomicAdd(&gsq[t], q);
}

// normalize; optionally pre-scale each row by dinv[row] (for the next SpMM)
__global__ __launch_bounds__(256) void k_bnnorm(const float* __restrict__ in,
                                                const float* __restrict__ gsum,
                                                const float* __restrict__ gsq,
                                                const float* __restrict__ g,
                                                const float* __restrict__ be,
                                                const float* __restrict__ dinv, int n,
                                                __hip_bfloat16* __restrict__ out) {
    int idx = blockIdx.x * blockDim.x + threadIdx.x;
    if (idx < n * HID) {
        int c = idx & (HID - 1);
        int row = idx >> 8;
        float invn = 1.0f / (float)n;
        float mean = gsum[c] * invn;
        float var = gsq[c] * invn - mean * mean;
        float sc = rsqrtf(var + BN_EPS) * g[c];
        float v = (in[idx] - mean) * sc + be[c];
        if (dinv) v *= dinv[row];
        out[idx] = __float2bfloat16(v);
    }
}

extern "C" void kernel_launch(void* const* d_in, const int* in_sizes, int n_in, void* d_out,
                              int out_size, void* d_ws, size_t ws_size, hipStream_t stream) {
    const float* x = (const float*)d_in[0];
    const int* ei = (const int*)d_in[1];
    const float* W1 = (const float*)d_in[2];
    const float* b1 = (const float*)d_in[3];
    const float* g1 = (const float*)d_in[4];
    const float* be1 = (const float*)d_in[5];
    const float* W2 = (const float*)d_in[6];
    const float* b2 = (const float*)d_in[7];
    const float* g2 = (const float*)d_in[8];
    const float* be2 = (const float*)d_in[9];
    const float* Wfc = (const float*)d_in[10];
    const float* bfc = (const float*)d_in[11];
    float* out = (float*)d_out;

    const int N = in_sizes[0] / NFEAT;  // 50000
    const int E = in_sizes[1] / 2;      // 800000

    char* ws = (char*)d_ws;
    size_t off = 0;
    auto alloc = [&](size_t bytes) -> void* {
        void* p = ws + off;
        off += (bytes + 255) & ~(size_t)255;
        return p;
    };
    int* row_cnt = (int*)alloc((size_t)N * 4);
    int* partial = (int*)alloc((size_t)N * 4);
    int* row_start = (int*)alloc((size_t)N * 4);
    int* cursor = (int*)alloc((size_t)N * 4);
    int* blk = (int*)alloc(256 * 4);
    float* dinv = (float*)alloc((size_t)N * 4);
    int* col_idx = (int*)alloc((size_t)E * 4);
    float* gstats = (float*)alloc(512 * 4);
    __hip_bfloat16* Wt1 = (__hip_bfloat16*)alloc(256 * 128 * 2);
    __hip_bfloat16* Wt2 = (__hip_bfloat16*)alloc(256 * 256 * 2);
    __hip_bfloat16* Wtf = (__hip_bfloat16*)alloc(256 * 256 * 2);
    // xs (N x 128 bf16) and aggX (N x 128 bf16) are contiguous; after GEMM1 both are
    // dead, so aggH (N x 256 bf16) reuses the same region.
    __hip_bfloat16* xs = (__hip_bfloat16*)alloc((size_t)N * NFEAT * 2 * 2);
    __hip_bfloat16* aggX = xs + (size_t)N * NFEAT;
    __hip_bfloat16* aggH = xs;
    __hip_bfloat16* bufB = (__hip_bfloat16*)alloc((size_t)N * HID * 2);  // BN out (bf16)
    float* bufF = (float*)alloc((size_t)N * HID * 4);                    // GEMM out (fp32)

    // CSR build + degrees
    hipMemsetAsync(row_cnt, 0, (size_t)N * 4, stream);
    k_count<<<(E + 255) / 256, 256, 0, stream>>>(ei, E, row_cnt);
    int nblk = (N + 255) / 256;  // 196 (<=256 so single-block scan2 works)
    k_scan1<<<nblk, 256, 0, stream>>>(row_cnt, N, partial, blk);
    k_scan2<<<1, 256, 0, stream>>>(blk, nblk);
    k_finalize<<<nblk, 256, 0, stream>>>(partial, blk, row_cnt, N, row_start, cursor, dinv);
    k_fill<<<(E + 255) / 256, 256, 0, stream>>>(ei, E, cursor, col_idx);

    // weights -> transposed bf16
    k_transpose<<<(128 * 256) / 256, 256, 0, stream>>>(W1, Wt1, 128, 256);
    k_transpose<<<(256 * 256) / 256, 256, 0, stream>>>(W2, Wt2, 256, 256);
    k_transpose<<<(256 * 256) / 256, 256, 0, stream>>>(Wfc, Wtf, 256, 256);

    // xs = dinv_row * x, bf16   (shift = log2(128/4) = 5)
    k_scale_cast<<<(N * NFEAT / 4 + 255) / 256, 256, 0, stream>>>(x, dinv, xs, 5, N * NFEAT / 4);

    dim3 gg((N + 63) / 64, 4);
    // Layer 1: aggregate-first on 128 channels, then GEMM
    k_spmm<NFEAT><<<N, 256, 0, stream>>>(xs, row_start, row_cnt, col_idx, dinv, aggX);
    k_gemm<<<gg, 256, 0, stream>>>(aggX, Wt1, b1, bufF, N, NFEAT);
    hipMemsetAsync(gstats, 0, 512 * 4, stream);
    k_bnstats<<<512, 256, 0, stream>>>(bufF, N, gstats, gstats + 256);
    k_bnnorm<<<(N * HID + 255) / 256, 256, 0, stream>>>(bufF, gstats, gstats + 256, g1, be1, dinv,
                                                        N, bufB);
    // Layer 2: aggregate-first on 256 channels, then GEMM
    k_spmm<HID><<<N, 256, 0, stream>>>(bufB, row_start, row_cnt, col_idx, dinv, aggH);
    k_gemm<<<gg, 256, 0, stream>>>(aggH, Wt2, b2, bufF, N, HID);
    hipMemsetAsync(gstats, 0, 512 * 4, stream);
    k_bnstats<<<512, 256, 0, stream>>>(bufF, N, gstats, gstats + 256);
    k_bnnorm<<<(N * HID + 255) / 256, 256, 0, stream>>>(bufF, gstats, gstats + 256, g2, be2,
                                                        nullptr, N, bufB);
    // Final linear (fp32 out + bias)
    k_gemm<<<gg, 256, 0, stream>>>(bufB, Wtf, bfc, out, N, HID);
}

// Round 4
// 460.968 us; speedup vs baseline: 1.6761x; 1.1779x over previous
//
#include <hip/hip_runtime.h>
#include <hip/hip_bf16.h>

#define NFEAT 128
#define HID 256
#define BN_EPS 1e-5f

typedef __attribute__((ext_vector_type(8))) __bf16 bf16x8;
typedef __attribute__((ext_vector_type(4))) float f32x4;

static __device__ __forceinline__ float bflo(unsigned u) {
    union { unsigned x; float f; } c; c.x = u << 16; return c.f;
}
static __device__ __forceinline__ float bfhi(unsigned u) {
    union { unsigned x; float f; } c; c.x = u & 0xffff0000u; return c.f;
}

// ---------- CSR build ----------
__global__ void k_count(const int* __restrict__ ei, int E, int* __restrict__ cnt) {
    int e = blockIdx.x * blockDim.x + threadIdx.x;
    if (e < E) atomicAdd(&cnt[ei[E + e]], 1);
}

__global__ void k_scan1(const int* __restrict__ cnt, int n, int* __restrict__ partial,
                        int* __restrict__ blk_total) {
    __shared__ int sh[256];
    int i = blockIdx.x * 256 + threadIdx.x;
    int v = (i < n) ? cnt[i] : 0;
    sh[threadIdx.x] = v;
    __syncthreads();
    for (int off = 1; off < 256; off <<= 1) {
        int x = (threadIdx.x >= off) ? sh[threadIdx.x - off] : 0;
        __syncthreads();
        sh[threadIdx.x] += x;
        __syncthreads();
    }
    if (i < n) partial[i] = sh[threadIdx.x] - v;
    if (threadIdx.x == 255) blk_total[blockIdx.x] = sh[255];
}

__global__ void k_scan2(int* __restrict__ blk, int nb) {
    __shared__ int sh[256];
    int t = threadIdx.x;
    int v = (t < nb) ? blk[t] : 0;
    sh[t] = v;
    __syncthreads();
    for (int off = 1; off < 256; off <<= 1) {
        int x = (t >= off) ? sh[t - off] : 0;
        __syncthreads();
        sh[t] += x;
        __syncthreads();
    }
    if (t < nb) blk[t] = sh[t] - v;
}

__global__ void k_finalize(const int* __restrict__ partial, const int* __restrict__ blk,
                           const int* __restrict__ cnt, int n, int* __restrict__ row_start,
                           int* __restrict__ cursor, float* __restrict__ dinv) {
    int i = blockIdx.x * blockDim.x + threadIdx.x;
    if (i < n) {
        int s = partial[i] + blk[i >> 8];
        row_start[i] = s;
        cursor[i] = s;
        dinv[i] = rsqrtf((float)(cnt[i] + 1));
    }
}

__global__ void k_fill(const int* __restrict__ ei, int E, int* __restrict__ cursor,
                       int* __restrict__ col) {
    int e = blockIdx.x * blockDim.x + threadIdx.x;
    if (e < E) {
        int d = ei[E + e];
        int pos = atomicAdd(&cursor[d], 1);
        col[pos] = ei[e];
    }
}

// ---------- fp32 -> bf16 cast with per-row dinv scale ----------
__global__ void k_scale_cast(const float* __restrict__ in, const float* __restrict__ dinv,
                             __hip_bfloat16* __restrict__ out, int shift, int n4) {
    int i = blockIdx.x * blockDim.x + threadIdx.x;
    if (i < n4) {
        float d = dinv[i >> shift];
        float4 v = *(const float4*)(in + (size_t)i * 4);
        __hip_bfloat16* o = out + (size_t)i * 4;
        o[0] = __float2bfloat16(v.x * d);
        o[1] = __float2bfloat16(v.y * d);
        o[2] = __float2bfloat16(v.z * d);
        o[3] = __float2bfloat16(v.w * d);
    }
}

// ---------- weight transpose+cast ----------
__global__ void k_transpose(const float* __restrict__ W, __hip_bfloat16* __restrict__ Wt, int K,
                            int Nc) {
    int idx = blockIdx.x * blockDim.x + threadIdx.x;
    if (idx < K * Nc) {
        int n = idx % Nc;
        int k = idx / Nc;
        Wt[n * K + k] = __float2bfloat16(W[k * Nc + n]);
    }
}

// ---------- wave-per-node SpMM, optional fused BN affine ----------
template <int PL>
static __device__ __forceinline__ void loadrow(const __hip_bfloat16* p, float* v) {
    if constexpr (PL == 4) {
        uint2 u = *(const uint2*)p;
        v[0] = bflo(u.x); v[1] = bfhi(u.x); v[2] = bflo(u.y); v[3] = bfhi(u.y);
    } else {
        unsigned u = *(const unsigned*)p;
        v[0] = bflo(u); v[1] = bfhi(u);
    }
}

// out_i = dinv_i * ( f(H_i)*w_i + sum_{j->i} f(H_j)*w_j )
//   BN:  f(h)=h*sc+sh (per channel), w=dinv  |  !BN: f(h)=h, w=1 (rows pre-scaled)
template <int C, bool BN>
__global__ __launch_bounds__(256) void k_spmm_w(
    const __hip_bfloat16* __restrict__ H, const int* __restrict__ rs,
    const int* __restrict__ rc, const int* __restrict__ col, const float* __restrict__ dinv,
    const float* __restrict__ gsum, const float* __restrict__ gsq,
    const float* __restrict__ gamma, const float* __restrict__ beta, float invN,
    __hip_bfloat16* __restrict__ out, int N) {
    constexpr int PL = C / 64;  // channels per lane
    const int wid = blockIdx.x * 4 + (threadIdx.x >> 6);
    if (wid >= N) return;
    const int lane = threadIdx.x & 63;
    const int ch = lane * PL;

    float sc[PL], sh[PL];
    if (BN) {
#pragma unroll
        for (int i = 0; i < PL; i++) {
            int c = ch + i;
            float mean = gsum[c] * invN;
            float var = gsq[c] * invN - mean * mean;
            float iv = rsqrtf(var + BN_EPS) * gamma[c];
            sc[i] = iv;
            sh[i] = beta[c] - mean * iv;
        }
    }
    const int s = rs[wid];
    const int deg = rc[wid];
    const float di = dinv[wid];

    float acc[PL];
    {
        float v[PL];
        loadrow<PL>(H + (size_t)wid * C + ch, v);
#pragma unroll
        for (int i = 0; i < PL; i++) acc[i] = BN ? (v[i] * sc[i] + sh[i]) * di : v[i];
    }
    int e = 0;
    for (; e + 4 <= deg; e += 4) {
        int i0 = col[s + e], i1 = col[s + e + 1], i2 = col[s + e + 2], i3 = col[s + e + 3];
        float v0[PL], v1[PL], v2[PL], v3[PL];
        loadrow<PL>(H + (size_t)i0 * C + ch, v0);
        loadrow<PL>(H + (size_t)i1 * C + ch, v1);
        loadrow<PL>(H + (size_t)i2 * C + ch, v2);
        loadrow<PL>(H + (size_t)i3 * C + ch, v3);
        if (BN) {
            float d0 = dinv[i0], d1 = dinv[i1], d2 = dinv[i2], d3 = dinv[i3];
#pragma unroll
            for (int i = 0; i < PL; i++)
                acc[i] += (v0[i] * sc[i] + sh[i]) * d0 + (v1[i] * sc[i] + sh[i]) * d1 +
                          (v2[i] * sc[i] + sh[i]) * d2 + (v3[i] * sc[i] + sh[i]) * d3;
        } else {
#pragma unroll
            for (int i = 0; i < PL; i++) acc[i] += v0[i] + v1[i] + v2[i] + v3[i];
        }
    }
    for (; e < deg; e++) {
        int i0 = col[s + e];
        float v0[PL];
        loadrow<PL>(H + (size_t)i0 * C + ch, v0);
        if (BN) {
            float d0 = dinv[i0];
#pragma unroll
            for (int i = 0; i < PL; i++) acc[i] += (v0[i] * sc[i] + sh[i]) * d0;
        } else {
#pragma unroll
            for (int i = 0; i < PL; i++) acc[i] += v0[i];
        }
    }
    union { unsigned u[PL / 2]; unsigned short us[PL]; } o;
#pragma unroll
    for (int i = 0; i < PL; i++) {
        __hip_bfloat16 b = __float2bfloat16(di * acc[i]);
        o.us[i] = *(unsigned short*)&b;
    }
    if constexpr (PL == 4)
        *(uint2*)(out + (size_t)wid * C + ch) = *(uint2*)o.u;
    else
        *(unsigned*)(out + (size_t)wid * C + ch) = o.u[0];
}

// ---------- bf16 MFMA GEMM: [M][256] = A[M][K] @ B[K][256] + bias ----------
// outb mode: bf16 out + fused per-channel (sum, sumsq) stats via shfl+LDS+atomics.
// outf mode: fp32 out (final layer).
__global__ __launch_bounds__(256) void k_gemm(const __hip_bfloat16* __restrict__ A,
                                              const __hip_bfloat16* __restrict__ Bt,
                                              const float* __restrict__ bias,
                                              __hip_bfloat16* __restrict__ outb,
                                              float* __restrict__ outf,
                                              float* __restrict__ gsum, float* __restrict__ gsq,
                                              int M, int K) {
    __shared__ __align__(16) unsigned short As[64 * 40];
    __shared__ __align__(16) unsigned short Bs[64 * 40];
    __shared__ float sred[4][64];
    __shared__ float qred[4][64];
    const int t = threadIdx.x;
    const int wv = t >> 6;
    const int lane = t & 63;
    const int mlane = lane & 15;
    const int quad = lane >> 4;
    const int m0 = blockIdx.x * 64;
    const int n0 = blockIdx.y * 64;
    const int lr = t >> 2;
    const int lk = (t & 3) * 8;
    const int arow = m0 + lr;

    f32x4 acc[4];
#pragma unroll
    for (int i = 0; i < 4; i++) acc[i] = (f32x4){0.f, 0.f, 0.f, 0.f};

    for (int k0 = 0; k0 < K; k0 += 32) {
        uint4 av = {0u, 0u, 0u, 0u};
        if (arow < M) av = *(const uint4*)(A + (size_t)arow * K + k0 + lk);
        *(uint4*)(As + lr * 40 + lk) = av;
        uint4 bv = *(const uint4*)(Bt + (size_t)(n0 + lr) * K + k0 + lk);
        *(uint4*)(Bs + lr * 40 + lk) = bv;
        __syncthreads();
        bf16x8 af = *(const bf16x8*)(As + (16 * wv + mlane) * 40 + quad * 8);
#pragma unroll
        for (int tt = 0; tt < 4; tt++) {
            bf16x8 bfr = *(const bf16x8*)(Bs + (16 * tt + mlane) * 40 + quad * 8);
            acc[tt] = __builtin_amdgcn_mfma_f32_16x16x32_bf16(af, bfr, acc[tt], 0, 0, 0);
        }
        __syncthreads();
    }
    // C/D mapping: col = lane&15, row = quad*4 + reg
    if (outb) {
        float sp[4], qp[4];
#pragma unroll
        for (int tt = 0; tt < 4; tt++) {
            int colx = n0 + 16 * tt + mlane;
            float bv = bias[colx];
            float s = 0.f, q = 0.f;
#pragma unroll
            for (int r = 0; r < 4; r++) {
                int row = m0 + 16 * wv + quad * 4 + r;
                if (row < M) {
                    float h = acc[tt][r] + bv;
                    outb[(size_t)row * HID + colx] = __float2bfloat16(h);
                    s += h;
                    q += h * h;
                }
            }
            sp[tt] = s;
            qp[tt] = q;
        }
#pragma unroll
        for (int tt = 0; tt < 4; tt++) {
            sp[tt] += __shfl_xor(sp[tt], 16);
            sp[tt] += __shfl_xor(sp[tt], 32);
            qp[tt] += __shfl_xor(qp[tt], 16);
            qp[tt] += __shfl_xor(qp[tt], 32);
        }
        if (quad == 0) {
#pragma unroll
            for (int tt = 0; tt < 4; tt++) {
                sred[wv][16 * tt + mlane] = sp[tt];
                qred[wv][16 * tt + mlane] = qp[tt];
            }
        }
        __syncthreads();
        if (t < 64) {
            float ss = sred[0][t] + sred[1][t] + sred[2][t] + sred[3][t];
            float qq = qred[0][t] + qred[1][t] + qred[2][t] + qred[3][t];
            atomicAdd(&gsum[n0 + t], ss);
            atomicAdd(&gsq[n0 + t], qq);
        }
    } else {
#pragma unroll
        for (int tt = 0; tt < 4; tt++) {
            int colx = n0 + 16 * tt + mlane;
            float bv = bias[colx];
#pragma unroll
            for (int r = 0; r < 4; r++) {
                int row = m0 + 16 * wv + quad * 4 + r;
                if (row < M) outf[(size_t)row * HID + colx] = acc[tt][r] + bv;
            }
        }
    }
}

// ---------- BN normalize (layer 2), bf16 in -> bf16 out, x4 vectorized ----------
__global__ __launch_bounds__(256) void k_bnnorm(const __hip_bfloat16* __restrict__ in,
                                                const float* __restrict__ gsum,
                                                const float* __restrict__ gsq,
                                                const float* __restrict__ g,
                                                const float* __restrict__ be, float invN,
                                                __hip_bfloat16* __restrict__ out, int n4) {
    int idx = blockIdx.x * blockDim.x + threadIdx.x;
    if (idx < n4) {
        int cbase = (idx * 4) & (HID - 1);
        uint2 u = *(const uint2*)(in + (size_t)idx * 4);
        float v[4] = {bflo(u.x), bfhi(u.x), bflo(u.y), bfhi(u.y)};
        union { unsigned w[2]; unsigned short us[4]; } o;
#pragma unroll
        for (int i = 0; i < 4; i++) {
            int c = cbase + i;
            float mean = gsum[c] * invN;
            float var = gsq[c] * invN - mean * mean;
            float sc = rsqrtf(var + BN_EPS) * g[c];
            __hip_bfloat16 b = __float2bfloat16((v[i] - mean) * sc + be[c]);
            o.us[i] = *(unsigned short*)&b;
        }
        *(uint2*)(out + (size_t)idx * 4) = *(uint2*)o.w;
    }
}

extern "C" void kernel_launch(void* const* d_in, const int* in_sizes, int n_in, void* d_out,
                              int out_size, void* d_ws, size_t ws_size, hipStream_t stream) {
    const float* x = (const float*)d_in[0];
    const int* ei = (const int*)d_in[1];
    const float* W1 = (const float*)d_in[2];
    const float* b1 = (const float*)d_in[3];
    const float* g1 = (const float*)d_in[4];
    const float* be1 = (const float*)d_in[5];
    const float* W2 = (const float*)d_in[6];
    const float* b2 = (const float*)d_in[7];
    const float* g2 = (const float*)d_in[8];
    const float* be2 = (const float*)d_in[9];
    const float* Wfc = (const float*)d_in[10];
    const float* bfc = (const float*)d_in[11];
    float* out = (float*)d_out;

    const int N = in_sizes[0] / NFEAT;  // 50000
    const int E = in_sizes[1] / 2;      // 800000
    const float invN = 1.0f / (float)N;

    char* ws = (char*)d_ws;
    size_t off = 0;
    auto alloc = [&](size_t bytes) -> void* {
        void* p = ws + off;
        off += (bytes + 255) & ~(size_t)255;
        return p;
    };
    int* row_cnt = (int*)alloc((size_t)N * 4);
    int* partial = (int*)alloc((size_t)N * 4);
    int* row_start = (int*)alloc((size_t)N * 4);
    int* cursor = (int*)alloc((size_t)N * 4);
    int* blk = (int*)alloc(256 * 4);
    float* dinv = (float*)alloc((size_t)N * 4);
    int* col_idx = (int*)alloc((size_t)E * 4);
    float* gs1 = (float*)alloc(512 * 4);  // layer1 sum/sumsq
    float* gs2 = (float*)alloc(512 * 4);  // layer2 sum/sumsq
    __hip_bfloat16* Wt1 = (__hip_bfloat16*)alloc(256 * 128 * 2);
    __hip_bfloat16* Wt2 = (__hip_bfloat16*)alloc(256 * 256 * 2);
    __hip_bfloat16* Wtf = (__hip_bfloat16*)alloc(256 * 256 * 2);
    // xs (N x128) + aggX (N x128) contiguous; both dead after gemm1 -> agg2 reuses.
    __hip_bfloat16* xs = (__hip_bfloat16*)alloc((size_t)N * NFEAT * 2 * 2);
    __hip_bfloat16* aggX = xs + (size_t)N * NFEAT;
    __hip_bfloat16* agg2 = xs;
    __hip_bfloat16* h1 = (__hip_bfloat16*)alloc((size_t)N * HID * 2);  // gemm1 out
    __hip_bfloat16* h2 = (__hip_bfloat16*)alloc((size_t)N * HID * 2);  // gemm2 out
    __hip_bfloat16* bufB = h1;                                         // bn2 out (h1 dead)

    // CSR build + degrees
    hipMemsetAsync(row_cnt, 0, (size_t)N * 4, stream);
    hipMemsetAsync(gs1, 0, 1024 * 4, stream);  // gs1+gs2 contiguous
    k_count<<<(E + 255) / 256, 256, 0, stream>>>(ei, E, row_cnt);
    int nblk = (N + 255) / 256;
    k_scan1<<<nblk, 256, 0, stream>>>(row_cnt, N, partial, blk);
    k_scan2<<<1, 256, 0, stream>>>(blk, nblk);
    k_finalize<<<nblk, 256, 0, stream>>>(partial, blk, row_cnt, N, row_start, cursor, dinv);
    k_fill<<<(E + 255) / 256, 256, 0, stream>>>(ei, E, cursor, col_idx);

    k_transpose<<<(128 * 256) / 256, 256, 0, stream>>>(W1, Wt1, 128, 256);
    k_transpose<<<(256 * 256) / 256, 256, 0, stream>>>(W2, Wt2, 256, 256);
    k_transpose<<<(256 * 256) / 256, 256, 0, stream>>>(Wfc, Wtf, 256, 256);

    // xs = dinv_row * x (bf16); shift = log2(128/4) = 5
    k_scale_cast<<<(N * NFEAT / 4 + 255) / 256, 256, 0, stream>>>(x, dinv, xs, 5, N * NFEAT / 4);

    dim3 gg((N + 63) / 64, 4);
    int sg = (N + 3) / 4;
    // Layer 1: aggregate (128ch) -> GEMM (+bias, fused stats)
    k_spmm_w<NFEAT, false><<<sg, 256, 0, stream>>>(xs, row_start, row_cnt, col_idx, dinv, nullptr,
                                                   nullptr, nullptr, nullptr, invN, aggX, N);
    k_gemm<<<gg, 256, 0, stream>>>(aggX, Wt1, b1, h1, nullptr, gs1, gs1 + 256, N, NFEAT);
    // Layer 2: aggregate with fused BN1 (256ch) -> GEMM (+bias, fused stats)
    k_spmm_w<HID, true><<<sg, 256, 0, stream>>>(h1, row_start, row_cnt, col_idx, dinv, gs1,
                                                gs1 + 256, g1, be1, invN, agg2, N);
    k_gemm<<<gg, 256, 0, stream>>>(agg2, Wt2, b2, h2, nullptr, gs2, gs2 + 256, N, HID);
    // BN2 -> final linear (fp32 out)
    k_bnnorm<<<(N * HID / 4 + 255) / 256, 256, 0, stream>>>(h2, gs2, gs2 + 256, g2, be2, invN,
                                                            bufB, N * HID / 4);
    k_gemm<<<gg, 256, 0, stream>>>(bufB, Wtf, bfc, nullptr, out, nullptr, nullptr, N, HID);
}

// Round 5
// 426.355 us; speedup vs baseline: 1.8122x; 1.0812x over previous
//
#include <hip/hip_runtime.h>
#include <hip/hip_bf16.h>

#define NFEAT 128
#define HID 256
#define BN_EPS 1e-5f

typedef __attribute__((ext_vector_type(8))) __bf16 bf16x8;
typedef __attribute__((ext_vector_type(4))) float f32x4;

static __device__ __forceinline__ float bflo(unsigned u) {
    union { unsigned x; float f; } c; c.x = u << 16; return c.f;
}
static __device__ __forceinline__ float bfhi(unsigned u) {
    union { unsigned x; float f; } c; c.x = u & 0xffff0000u; return c.f;
}

// ---------- CSR build ----------
// count + per-edge rank (stable slot among same-dst edges)
__global__ void k_count(const int* __restrict__ ei, int E, int* __restrict__ cnt,
                        int* __restrict__ rank) {
    int e = blockIdx.x * blockDim.x + threadIdx.x;
    if (e < E) rank[e] = atomicAdd(&cnt[ei[E + e]], 1);
}

__global__ void k_scan1(const int* __restrict__ cnt, int n, int* __restrict__ partial,
                        int* __restrict__ blk_total) {
    __shared__ int sh[256];
    int i = blockIdx.x * 256 + threadIdx.x;
    int v = (i < n) ? cnt[i] : 0;
    sh[threadIdx.x] = v;
    __syncthreads();
    for (int off = 1; off < 256; off <<= 1) {
        int x = (threadIdx.x >= off) ? sh[threadIdx.x - off] : 0;
        __syncthreads();
        sh[threadIdx.x] += x;
        __syncthreads();
    }
    if (i < n) partial[i] = sh[threadIdx.x] - v;
    if (threadIdx.x == 255) blk_total[blockIdx.x] = sh[255];
}

__global__ void k_scan2(int* __restrict__ blk, int nb) {
    __shared__ int sh[256];
    int t = threadIdx.x;
    int v = (t < nb) ? blk[t] : 0;
    sh[t] = v;
    __syncthreads();
    for (int off = 1; off < 256; off <<= 1) {
        int x = (t >= off) ? sh[t - off] : 0;
        __syncthreads();
        sh[t] += x;
        __syncthreads();
    }
    if (t < nb) blk[t] = sh[t] - v;
}

__global__ void k_finalize(const int* __restrict__ partial, const int* __restrict__ blk,
                           const int* __restrict__ cnt, int n, int* __restrict__ row_start,
                           float* __restrict__ dinv) {
    int i = blockIdx.x * blockDim.x + threadIdx.x;
    if (i < n) {
        row_start[i] = partial[i] + blk[i >> 8];
        dinv[i] = rsqrtf((float)(cnt[i] + 1));
    }
}

// atomic-free fill using precomputed ranks
__global__ void k_fill(const int* __restrict__ ei, const int* __restrict__ rank,
                       const int* __restrict__ row_start, int E, int* __restrict__ col) {
    int e = blockIdx.x * blockDim.x + threadIdx.x;
    if (e < E) {
        int d = ei[E + e];
        col[row_start[d] + rank[e]] = ei[e];
    }
}

// ---------- fp32 -> bf16 cast with per-row dinv scale ----------
__global__ void k_scale_cast(const float* __restrict__ in, const float* __restrict__ dinv,
                             __hip_bfloat16* __restrict__ out, int shift, int n4) {
    int i = blockIdx.x * blockDim.x + threadIdx.x;
    if (i < n4) {
        float d = dinv[i >> shift];
        float4 v = *(const float4*)(in + (size_t)i * 4);
        __hip_bfloat16* o = out + (size_t)i * 4;
        o[0] = __float2bfloat16(v.x * d);
        o[1] = __float2bfloat16(v.y * d);
        o[2] = __float2bfloat16(v.z * d);
        o[3] = __float2bfloat16(v.w * d);
    }
}

// ---------- all 3 weight transposes in one dispatch ----------
__global__ void k_transpose3(const float* __restrict__ W1, const float* __restrict__ W2,
                             const float* __restrict__ Wf, __hip_bfloat16* __restrict__ Wt1,
                             __hip_bfloat16* __restrict__ Wt2, __hip_bfloat16* __restrict__ Wtf) {
    int idx = blockIdx.x * 256 + threadIdx.x;  // 0 .. 163839
    const float* W;
    __hip_bfloat16* Wt;
    int K, base;
    if (idx < 32768) { W = W1; Wt = Wt1; K = 128; base = idx; }
    else if (idx < 98304) { W = W2; Wt = Wt2; K = 256; base = idx - 32768; }
    else { W = Wf; Wt = Wtf; K = 256; base = idx - 98304; }
    int n = base & 255;
    int k = base >> 8;
    if (k < K) Wt[n * K + k] = __float2bfloat16(W[k * 256 + n]);
}

// ---------- wave-per-node pure-add SpMM on pre-scaled rows ----------
template <int PL>
static __device__ __forceinline__ void loadrow(const __hip_bfloat16* p, float* v) {
    if constexpr (PL == 4) {
        uint2 u = *(const uint2*)p;
        v[0] = bflo(u.x); v[1] = bfhi(u.x); v[2] = bflo(u.y); v[3] = bfhi(u.y);
    } else {
        unsigned u = *(const unsigned*)p;
        v[0] = bflo(u); v[1] = bfhi(u);
    }
}

// out_i = dinv_i * ( Hs_i + sum_{j->i} Hs_j ), Hs rows pre-scaled by dinv_j
template <int C>
__global__ __launch_bounds__(256) void k_spmm_w(const __hip_bfloat16* __restrict__ Hs,
                                                const int* __restrict__ rs,
                                                const int* __restrict__ rc,
                                                const int* __restrict__ col,
                                                const float* __restrict__ dinv,
                                                __hip_bfloat16* __restrict__ out, int N) {
    constexpr int PL = C / 64;  // channels per lane
    const int wid = blockIdx.x * 4 + (threadIdx.x >> 6);
    if (wid >= N) return;
    const int lane = threadIdx.x & 63;
    const int ch = lane * PL;
    const int s = rs[wid];
    const int deg = rc[wid];
    const float di = dinv[wid];

    float acc[PL];
    loadrow<PL>(Hs + (size_t)wid * C + ch, acc);  // self-loop term

    int e = 0;
    for (; e + 8 <= deg; e += 8) {
        int idx[8];
#pragma unroll
        for (int j = 0; j < 8; j++) idx[j] = col[s + e + j];
        float v[8][PL];
#pragma unroll
        for (int j = 0; j < 8; j++) loadrow<PL>(Hs + (size_t)idx[j] * C + ch, v[j]);
#pragma unroll
        for (int j = 0; j < 8; j++)
#pragma unroll
            for (int i = 0; i < PL; i++) acc[i] += v[j][i];
    }
    for (; e < deg; e++) {
        int i0 = col[s + e];
        float v0[PL];
        loadrow<PL>(Hs + (size_t)i0 * C + ch, v0);
#pragma unroll
        for (int i = 0; i < PL; i++) acc[i] += v0[i];
    }
    union { unsigned u[PL / 2]; unsigned short us[PL]; } o;
#pragma unroll
    for (int i = 0; i < PL; i++) {
        __hip_bfloat16 b = __float2bfloat16(di * acc[i]);
        o.us[i] = *(unsigned short*)&b;
    }
    if constexpr (PL == 4)
        *(uint2*)(out + (size_t)wid * C + ch) = *(uint2*)o.u;
    else
        *(unsigned*)(out + (size_t)wid * C + ch) = o.u[0];
}

// ---------- bf16 MFMA GEMM: [M][256] = A[M][K] @ B[K][256] + bias ----------
// outb mode: bf16 out + fused per-channel (sum, sumsq) stats. outf mode: fp32 out.
__global__ __launch_bounds__(256) void k_gemm(const __hip_bfloat16* __restrict__ A,
                                              const __hip_bfloat16* __restrict__ Bt,
                                              const float* __restrict__ bias,
                                              __hip_bfloat16* __restrict__ outb,
                                              float* __restrict__ outf,
                                              float* __restrict__ gsum, float* __restrict__ gsq,
                                              int M, int K) {
    __shared__ __align__(16) unsigned short As[64 * 40];
    __shared__ __align__(16) unsigned short Bs[64 * 40];
    __shared__ float sred[4][64];
    __shared__ float qred[4][64];
    const int t = threadIdx.x;
    const int wv = t >> 6;
    const int lane = t & 63;
    const int mlane = lane & 15;
    const int quad = lane >> 4;
    const int m0 = blockIdx.x * 64;
    const int n0 = blockIdx.y * 64;
    const int lr = t >> 2;
    const int lk = (t & 3) * 8;
    const int arow = m0 + lr;

    f32x4 acc[4];
#pragma unroll
    for (int i = 0; i < 4; i++) acc[i] = (f32x4){0.f, 0.f, 0.f, 0.f};

    for (int k0 = 0; k0 < K; k0 += 32) {
        uint4 av = {0u, 0u, 0u, 0u};
        if (arow < M) av = *(const uint4*)(A + (size_t)arow * K + k0 + lk);
        *(uint4*)(As + lr * 40 + lk) = av;
        uint4 bv = *(const uint4*)(Bt + (size_t)(n0 + lr) * K + k0 + lk);
        *(uint4*)(Bs + lr * 40 + lk) = bv;
        __syncthreads();
        bf16x8 af = *(const bf16x8*)(As + (16 * wv + mlane) * 40 + quad * 8);
#pragma unroll
        for (int tt = 0; tt < 4; tt++) {
            bf16x8 bfr = *(const bf16x8*)(Bs + (16 * tt + mlane) * 40 + quad * 8);
            acc[tt] = __builtin_amdgcn_mfma_f32_16x16x32_bf16(af, bfr, acc[tt], 0, 0, 0);
        }
        __syncthreads();
    }
    // C/D mapping: col = lane&15, row = quad*4 + reg
    if (outb) {
        float sp[4], qp[4];
#pragma unroll
        for (int tt = 0; tt < 4; tt++) {
            int colx = n0 + 16 * tt + mlane;
            float bv = bias[colx];
            float s = 0.f, q = 0.f;
#pragma unroll
            for (int r = 0; r < 4; r++) {
                int row = m0 + 16 * wv + quad * 4 + r;
                if (row < M) {
                    float h = acc[tt][r] + bv;
                    outb[(size_t)row * HID + colx] = __float2bfloat16(h);
                    s += h;
                    q += h * h;
                }
            }
            sp[tt] = s;
            qp[tt] = q;
        }
#pragma unroll
        for (int tt = 0; tt < 4; tt++) {
            sp[tt] += __shfl_xor(sp[tt], 16);
            sp[tt] += __shfl_xor(sp[tt], 32);
            qp[tt] += __shfl_xor(qp[tt], 16);
            qp[tt] += __shfl_xor(qp[tt], 32);
        }
        if (quad == 0) {
#pragma unroll
            for (int tt = 0; tt < 4; tt++) {
                sred[wv][16 * tt + mlane] = sp[tt];
                qred[wv][16 * tt + mlane] = qp[tt];
            }
        }
        __syncthreads();
        if (t < 64) {
            float ss = sred[0][t] + sred[1][t] + sred[2][t] + sred[3][t];
            float qq = qred[0][t] + qred[1][t] + qred[2][t] + qred[3][t];
            atomicAdd(&gsum[n0 + t], ss);
            atomicAdd(&gsq[n0 + t], qq);
        }
    } else {
#pragma unroll
        for (int tt = 0; tt < 4; tt++) {
            int colx = n0 + 16 * tt + mlane;
            float bv = bias[colx];
#pragma unroll
            for (int r = 0; r < 4; r++) {
                int row = m0 + 16 * wv + quad * 4 + r;
                if (row < M) outf[(size_t)row * HID + colx] = acc[tt][r] + bv;
            }
        }
    }
}

// ---------- BN normalize, bf16 in -> bf16 out, optional per-row dinv scale ----------
__global__ __launch_bounds__(256) void k_bnnorm(const __hip_bfloat16* __restrict__ in,
                                                const float* __restrict__ gsum,
                                                const float* __restrict__ gsq,
                                                const float* __restrict__ g,
                                                const float* __restrict__ be,
                                                const float* __restrict__ dinv, float invN,
                                                __hip_bfloat16* __restrict__ out, int n4) {
    int idx = blockIdx.x * blockDim.x + threadIdx.x;
    if (idx < n4) {
        int cbase = (idx * 4) & (HID - 1);
        int row = (idx * 4) >> 8;
        float rowsc = dinv ? dinv[row] : 1.0f;
        uint2 u = *(const uint2*)(in + (size_t)idx * 4);
        float v[4] = {bflo(u.x), bfhi(u.x), bflo(u.y), bfhi(u.y)};
        union { unsigned w[2]; unsigned short us[4]; } o;
#pragma unroll
        for (int i = 0; i < 4; i++) {
            int c = cbase + i;
            float mean = gsum[c] * invN;
            float var = gsq[c] * invN - mean * mean;
            float sc = rsqrtf(var + BN_EPS) * g[c];
            __hip_bfloat16 b = __float2bfloat16(((v[i] - mean) * sc + be[c]) * rowsc);
            o.us[i] = *(unsigned short*)&b;
        }
        *(uint2*)(out + (size_t)idx * 4) = *(uint2*)o.w;
    }
}

extern "C" void kernel_launch(void* const* d_in, const int* in_sizes, int n_in, void* d_out,
                              int out_size, void* d_ws, size_t ws_size, hipStream_t stream) {
    const float* x = (const float*)d_in[0];
    const int* ei = (const int*)d_in[1];
    const float* W1 = (const float*)d_in[2];
    const float* b1 = (const float*)d_in[3];
    const float* g1 = (const float*)d_in[4];
    const float* be1 = (const float*)d_in[5];
    const float* W2 = (const float*)d_in[6];
    const float* b2 = (const float*)d_in[7];
    const float* g2 = (const float*)d_in[8];
    const float* be2 = (const float*)d_in[9];
    const float* Wfc = (const float*)d_in[10];
    const float* bfc = (const float*)d_in[11];
    float* out = (float*)d_out;

    const int N = in_sizes[0] / NFEAT;  // 50000
    const int E = in_sizes[1] / 2;      // 800000
    const float invN = 1.0f / (float)N;

    char* ws = (char*)d_ws;
    size_t off = 0;
    auto alloc = [&](size_t bytes) -> void* {
        void* p = ws + off;
        off += (bytes + 255) & ~(size_t)255;
        return p;
    };
    int* row_cnt = (int*)alloc((size_t)N * 4);
    int* partial = (int*)alloc((size_t)N * 4);
    int* row_start = (int*)alloc((size_t)N * 4);
    int* blk = (int*)alloc(256 * 4);
    float* dinv = (float*)alloc((size_t)N * 4);
    int* rank = (int*)alloc((size_t)E * 4);
    int* col_idx = (int*)alloc((size_t)E * 4);
    float* gs1 = (float*)alloc(512 * 4);
    float* gs2 = (float*)alloc(512 * 4);
    __hip_bfloat16* Wt1 = (__hip_bfloat16*)alloc(256 * 128 * 2);
    __hip_bfloat16* Wt2 = (__hip_bfloat16*)alloc(256 * 256 * 2);
    __hip_bfloat16* Wtf = (__hip_bfloat16*)alloc(256 * 256 * 2);
    // xs (N x128) + aggX (N x128) contiguous; both dead after gemm1 -> agg2 reuses.
    __hip_bfloat16* xs = (__hip_bfloat16*)alloc((size_t)N * NFEAT * 2 * 2);
    __hip_bfloat16* aggX = xs + (size_t)N * NFEAT;
    __hip_bfloat16* agg2 = xs;
    __hip_bfloat16* h1 = (__hip_bfloat16*)alloc((size_t)N * HID * 2);  // gemm1 out / bn1 in-place
    __hip_bfloat16* h2 = (__hip_bfloat16*)alloc((size_t)N * HID * 2);  // gemm2 out
    __hip_bfloat16* bufB = h1;                                         // bn2 out (h1 dead)

    hipMemsetAsync(row_cnt, 0, (size_t)N * 4, stream);
    hipMemsetAsync(gs1, 0, 1024 * 4, stream);  // gs1+gs2 contiguous

    // CSR build
    k_count<<<(E + 255) / 256, 256, 0, stream>>>(ei, E, row_cnt, rank);
    int nblk = (N + 255) / 256;
    k_scan1<<<nblk, 256, 0, stream>>>(row_cnt, N, partial, blk);
    k_scan2<<<1, 256, 0, stream>>>(blk, nblk);
    k_finalize<<<nblk, 256, 0, stream>>>(partial, blk, row_cnt, N, row_start, dinv);
    k_fill<<<(E + 255) / 256, 256, 0, stream>>>(ei, rank, row_start, E, col_idx);

    k_transpose3<<<640, 256, 0, stream>>>(W1, W2, Wfc, Wt1, Wt2, Wtf);

    // xs = dinv_row * x (bf16); shift = log2(128/4) = 5
    k_scale_cast<<<(N * NFEAT / 4 + 255) / 256, 256, 0, stream>>>(x, dinv, xs, 5, N * NFEAT / 4);

    dim3 gg((N + 63) / 64, 4);
    int sg = (N + 3) / 4;
    // Layer 1: aggregate (128ch, pure add) -> GEMM (+bias, fused stats)
    k_spmm_w<NFEAT><<<sg, 256, 0, stream>>>(xs, row_start, row_cnt, col_idx, dinv, aggX, N);
    k_gemm<<<gg, 256, 0, stream>>>(aggX, Wt1, b1, h1, nullptr, gs1, gs1 + 256, N, NFEAT);
    // BN1 (+dinv pre-scale, in place) -> Layer 2 aggregate (256ch) -> GEMM
    k_bnnorm<<<(N * HID / 4 + 255) / 256, 256, 0, stream>>>(h1, gs1, gs1 + 256, g1, be1, dinv,
                                                            invN, h1, N * HID / 4);
    k_spmm_w<HID><<<sg, 256, 0, stream>>>(h1, row_start, row_cnt, col_idx, dinv, agg2, N);
    k_gemm<<<gg, 256, 0, stream>>>(agg2, Wt2, b2, h2, nullptr, gs2, gs2 + 256, N, HID);
    // BN2 -> final linear (fp32 out)
    k_bnnorm<<<(N * HID / 4 + 255) / 256, 256, 0, stream>>>(h2, gs2, gs2 + 256, g2, be2, nullptr,
                                                            invN, bufB, N * HID / 4);
    k_gemm<<<gg, 256, 0, stream>>>(bufB, Wtf, bfc, nullptr, out, nullptr, nullptr, N, HID);
}

// Round 6
// 414.549 us; speedup vs baseline: 1.8638x; 1.0285x over previous
//
#include <hip/hip_runtime.h>
#include <hip/hip_bf16.h>

#define NFEAT 128
#define HID 256
#define BN_EPS 1e-5f

typedef __attribute__((ext_vector_type(8))) __bf16 bf16x8;
typedef __attribute__((ext_vector_type(4))) float f32x4;

static __device__ __forceinline__ float bflo(unsigned u) {
    union { unsigned x; float f; } c; c.x = u << 16; return c.f;
}
static __device__ __forceinline__ float bfhi(unsigned u) {
    union { unsigned x; float f; } c; c.x = u & 0xffff0000u; return c.f;
}

// ---------- CSR build ----------
__global__ void k_count(const int* __restrict__ ei, int E, int* __restrict__ cnt,
                        int* __restrict__ rank) {
    int e = blockIdx.x * blockDim.x + threadIdx.x;
    if (e < E) rank[e] = atomicAdd(&cnt[ei[E + e]], 1);
}

__global__ void k_scan1(const int* __restrict__ cnt, int n, int* __restrict__ partial,
                        int* __restrict__ blk_total) {
    __shared__ int sh[256];
    int i = blockIdx.x * 256 + threadIdx.x;
    int v = (i < n) ? cnt[i] : 0;
    sh[threadIdx.x] = v;
    __syncthreads();
    for (int off = 1; off < 256; off <<= 1) {
        int x = (threadIdx.x >= off) ? sh[threadIdx.x - off] : 0;
        __syncthreads();
        sh[threadIdx.x] += x;
        __syncthreads();
    }
    if (i < n) partial[i] = sh[threadIdx.x] - v;
    if (threadIdx.x == 255) blk_total[blockIdx.x] = sh[255];
}

__global__ void k_scan2(int* __restrict__ blk, int nb) {
    __shared__ int sh[256];
    int t = threadIdx.x;
    int v = (t < nb) ? blk[t] : 0;
    sh[t] = v;
    __syncthreads();
    for (int off = 1; off < 256; off <<= 1) {
        int x = (t >= off) ? sh[t - off] : 0;
        __syncthreads();
        sh[t] += x;
        __syncthreads();
    }
    if (t < nb) blk[t] = sh[t] - v;
}

__global__ void k_finalize(const int* __restrict__ partial, const int* __restrict__ blk,
                           const int* __restrict__ cnt, int n, int* __restrict__ row_start,
                           float* __restrict__ dinv) {
    int i = blockIdx.x * blockDim.x + threadIdx.x;
    if (i < n) {
        row_start[i] = partial[i] + blk[i >> 8];
        dinv[i] = rsqrtf((float)(cnt[i] + 1));
    }
}

__global__ void k_fill(const int* __restrict__ ei, const int* __restrict__ rank,
                       const int* __restrict__ row_start, int E, int* __restrict__ col) {
    int e = blockIdx.x * blockDim.x + threadIdx.x;
    if (e < E) {
        int d = ei[E + e];
        col[row_start[d] + rank[e]] = ei[e];
    }
}

// ---------- fp32 -> bf16 cast with per-row dinv scale ----------
__global__ void k_scale_cast(const float* __restrict__ in, const float* __restrict__ dinv,
                             __hip_bfloat16* __restrict__ out, int shift, int n4) {
    int i = blockIdx.x * blockDim.x + threadIdx.x;
    if (i < n4) {
        float d = dinv[i >> shift];
        float4 v = *(const float4*)(in + (size_t)i * 4);
        __hip_bfloat16* o = out + (size_t)i * 4;
        o[0] = __float2bfloat16(v.x * d);
        o[1] = __float2bfloat16(v.y * d);
        o[2] = __float2bfloat16(v.z * d);
        o[3] = __float2bfloat16(v.w * d);
    }
}

// ---------- all 3 weight transposes in one dispatch ----------
__global__ void k_transpose3(const float* __restrict__ W1, const float* __restrict__ W2,
                             const float* __restrict__ Wf, __hip_bfloat16* __restrict__ Wt1,
                             __hip_bfloat16* __restrict__ Wt2, __hip_bfloat16* __restrict__ Wtf) {
    int idx = blockIdx.x * 256 + threadIdx.x;
    const float* W;
    __hip_bfloat16* Wt;
    int K, base;
    if (idx < 32768) { W = W1; Wt = Wt1; K = 128; base = idx; }
    else if (idx < 98304) { W = W2; Wt = Wt2; K = 256; base = idx - 32768; }
    else { W = Wf; Wt = Wtf; K = 256; base = idx - 98304; }
    int n = base & 255;
    int k = base >> 8;
    if (k < K) Wt[n * K + k] = __float2bfloat16(W[k * 256 + n]);
}

// ---------- wave-per-node pure-add SpMM on pre-scaled rows ----------
template <int PL>
static __device__ __forceinline__ void loadrow(const __hip_bfloat16* p, float* v) {
    if constexpr (PL == 4) {
        uint2 u = *(const uint2*)p;
        v[0] = bflo(u.x); v[1] = bfhi(u.x); v[2] = bflo(u.y); v[3] = bfhi(u.y);
    } else {
        unsigned u = *(const unsigned*)p;
        v[0] = bflo(u); v[1] = bfhi(u);
    }
}

template <int C>
__global__ __launch_bounds__(256) void k_spmm_w(const __hip_bfloat16* __restrict__ Hs,
                                                const int* __restrict__ rs,
                                                const int* __restrict__ rc,
                                                const int* __restrict__ col,
                                                const float* __restrict__ dinv,
                                                __hip_bfloat16* __restrict__ out, int N) {
    constexpr int PL = C / 64;
    const int wid = blockIdx.x * 4 + (threadIdx.x >> 6);
    if (wid >= N) return;
    const int lane = threadIdx.x & 63;
    const int ch = lane * PL;
    const int s = rs[wid];
    const int deg = rc[wid];
    const float di = dinv[wid];

    float acc[PL];
    loadrow<PL>(Hs + (size_t)wid * C + ch, acc);  // self-loop term

    int e = 0;
    for (; e + 8 <= deg; e += 8) {
        int idx[8];
#pragma unroll
        for (int j = 0; j < 8; j++) idx[j] = col[s + e + j];
        float v[8][PL];
#pragma unroll
        for (int j = 0; j < 8; j++) loadrow<PL>(Hs + (size_t)idx[j] * C + ch, v[j]);
#pragma unroll
        for (int j = 0; j < 8; j++)
#pragma unroll
            for (int i = 0; i < PL; i++) acc[i] += v[j][i];
    }
    for (; e < deg; e++) {
        int i0 = col[s + e];
        float v0[PL];
        loadrow<PL>(Hs + (size_t)i0 * C + ch, v0);
#pragma unroll
        for (int i = 0; i < PL; i++) acc[i] += v0[i];
    }
    union { unsigned u[PL / 2]; unsigned short us[PL]; } o;
#pragma unroll
    for (int i = 0; i < PL; i++) {
        __hip_bfloat16 b = __float2bfloat16(di * acc[i]);
        o.us[i] = *(unsigned short*)&b;
    }
    if constexpr (PL == 4)
        *(uint2*)(out + (size_t)wid * C + ch) = *(uint2*)o.u;
    else
        *(unsigned*)(out + (size_t)wid * C + ch) = o.u[0];
}

// ---------- single-barrier MFMA GEMM ----------
// out[M][256] = A[M][K] @ B[K][256] + bias.  Block = 64 rows x 128 cols, grid (M/64, 2).
// B slice (128 cols x K) staged to LDS ONCE (all loads in flight, one barrier).
// A fragments load DIRECTLY global->VGPR (A-operand layout A[m=lane&15][k=quad*8+j] is a
// contiguous 16B row chunk) — no second barrier, no per-iteration sync.
// outb mode: bf16 out + fused BN stats; outf mode: fp32 out.
// NOTE: last block reads A rows >= M (stays inside d_ws; results discarded by store guard).
template <int K>
__global__ __launch_bounds__(256) void k_gemm2(const __hip_bfloat16* __restrict__ A,
                                               const __hip_bfloat16* __restrict__ Bt,
                                               const float* __restrict__ bias,
                                               __hip_bfloat16* __restrict__ outb,
                                               float* __restrict__ outf,
                                               float* __restrict__ gsum, float* __restrict__ gsq,
                                               int M) {
    constexpr int KS = K / 32;       // MFMA k-steps
    constexpr int LDR = K + 8;       // LDS row stride (elems): +16B pad -> <=2-way read alias
    constexpr int ROWU4 = K / 8;     // uint4 per B row
    __shared__ __align__(16) unsigned short Bs[128 * LDR];
    __shared__ float sred[4][128];
    __shared__ float qred[4][128];

    const int t = threadIdx.x;
    const int wv = t >> 6;
    const int lane = t & 63;
    const int mlane = lane & 15;
    const int quad = lane >> 4;
    const int m0 = blockIdx.x * 64;
    const int n0 = blockIdx.y * 128;

    // A fragments: wave wv covers rows m0+wv*16 .. +15; lane's operand row = m0+wv*16+mlane
    const int arow = m0 + wv * 16 + mlane;
    bf16x8 a[KS];
#pragma unroll
    for (int ks = 0; ks < KS; ks++)
        a[ks] = *(const bf16x8*)(A + (size_t)arow * K + ks * 32 + quad * 8);

    // stage B slice: Bt[n0..n0+128][0..K] -> Bs (coalesced, all 16B loads in flight)
#pragma unroll
    for (int i = 0; i < 128 * ROWU4 / 256; i++) {
        int idx = t + i * 256;
        int row = idx / ROWU4;
        int c = idx % ROWU4;
        uint4 v = *(const uint4*)(Bt + (size_t)(n0 + row) * K + c * 8);
        *(uint4*)(Bs + row * LDR + c * 8) = v;
    }
    __syncthreads();  // the ONLY barrier before the epilogue

    f32x4 acc[8];
#pragma unroll
    for (int i = 0; i < 8; i++) acc[i] = (f32x4){0.f, 0.f, 0.f, 0.f};

#pragma unroll
    for (int nt = 0; nt < 8; nt++) {
        const unsigned short* bp = Bs + (nt * 16 + mlane) * LDR + quad * 8;
#pragma unroll
        for (int ks = 0; ks < KS; ks++) {
            bf16x8 b = *(const bf16x8*)(bp + ks * 32);
            acc[nt] = __builtin_amdgcn_mfma_f32_16x16x32_bf16(a[ks], b, acc[nt], 0, 0, 0);
        }
    }

    // C/D mapping: col = lane&15, row = quad*4 + reg
    if (outb) {
        float sp[8], qp[8];
#pragma unroll
        for (int nt = 0; nt < 8; nt++) {
            int colx = n0 + nt * 16 + mlane;
            float bv = bias[colx];
            float s = 0.f, q = 0.f;
#pragma unroll
            for (int r = 0; r < 4; r++) {
                int row = m0 + wv * 16 + quad * 4 + r;
                if (row < M) {
                    float h = acc[nt][r] + bv;
                    outb[(size_t)row * HID + colx] = __float2bfloat16(h);
                    s += h;
                    q += h * h;
                }
            }
            sp[nt] = s;
            qp[nt] = q;
        }
#pragma unroll
        for (int nt = 0; nt < 8; nt++) {
            sp[nt] += __shfl_xor(sp[nt], 16);
            sp[nt] += __shfl_xor(sp[nt], 32);
            qp[nt] += __shfl_xor(qp[nt], 16);
            qp[nt] += __shfl_xor(qp[nt], 32);
        }
        if (quad == 0) {
#pragma unroll
            for (int nt = 0; nt < 8; nt++) {
                sred[wv][nt * 16 + mlane] = sp[nt];
                qred[wv][nt * 16 + mlane] = qp[nt];
            }
        }
        __syncthreads();
        if (t < 128) {
            float ss = sred[0][t] + sred[1][t] + sred[2][t] + sred[3][t];
            float qq = qred[0][t] + qred[1][t] + qred[2][t] + qred[3][t];
            atomicAdd(&gsum[n0 + t], ss);
            atomicAdd(&gsq[n0 + t], qq);
        }
    } else {
#pragma unroll
        for (int nt = 0; nt < 8; nt++) {
            int colx = n0 + nt * 16 + mlane;
            float bv = bias[colx];
#pragma unroll
            for (int r = 0; r < 4; r++) {
                int row = m0 + wv * 16 + quad * 4 + r;
                if (row < M) outf[(size_t)row * HID + colx] = acc[nt][r] + bv;
            }
        }
    }
}

// ---------- BN normalize, bf16 in -> bf16 out, optional per-row dinv scale ----------
__global__ __launch_bounds__(256) void k_bnnorm(const __hip_bfloat16* __restrict__ in,
                                                const float* __restrict__ gsum,
                                                const float* __restrict__ gsq,
                                                const float* __restrict__ g,
                                                const float* __restrict__ be,
                                                const float* __restrict__ dinv, float invN,
                                                __hip_bfloat16* __restrict__ out, int n4) {
    int idx = blockIdx.x * blockDim.x + threadIdx.x;
    if (idx < n4) {
        int cbase = (idx * 4) & (HID - 1);
        int row = (idx * 4) >> 8;
        float rowsc = dinv ? dinv[row] : 1.0f;
        uint2 u = *(const uint2*)(in + (size_t)idx * 4);
        float v[4] = {bflo(u.x), bfhi(u.x), bflo(u.y), bfhi(u.y)};
        union { unsigned w[2]; unsigned short us[4]; } o;
#pragma unroll
        for (int i = 0; i < 4; i++) {
            int c = cbase + i;
            float mean = gsum[c] * invN;
            float var = gsq[c] * invN - mean * mean;
            float sc = rsqrtf(var + BN_EPS) * g[c];
            __hip_bfloat16 b = __float2bfloat16(((v[i] - mean) * sc + be[c]) * rowsc);
            o.us[i] = *(unsigned short*)&b;
        }
        *(uint2*)(out + (size_t)idx * 4) = *(uint2*)o.w;
    }
}

extern "C" void kernel_launch(void* const* d_in, const int* in_sizes, int n_in, void* d_out,
                              int out_size, void* d_ws, size_t ws_size, hipStream_t stream) {
    const float* x = (const float*)d_in[0];
    const int* ei = (const int*)d_in[1];
    const float* W1 = (const float*)d_in[2];
    const float* b1 = (const float*)d_in[3];
    const float* g1 = (const float*)d_in[4];
    const float* be1 = (const float*)d_in[5];
    const float* W2 = (const float*)d_in[6];
    const float* b2 = (const float*)d_in[7];
    const float* g2 = (const float*)d_in[8];
    const float* be2 = (const float*)d_in[9];
    const float* Wfc = (const float*)d_in[10];
    const float* bfc = (const float*)d_in[11];
    float* out = (float*)d_out;

    const int N = in_sizes[0] / NFEAT;  // 50000
    const int E = in_sizes[1] / 2;      // 800000
    const float invN = 1.0f / (float)N;

    char* ws = (char*)d_ws;
    size_t off = 0;
    auto alloc = [&](size_t bytes) -> void* {
        void* p = ws + off;
        off += (bytes + 255) & ~(size_t)255;
        return p;
    };
    int* row_cnt = (int*)alloc((size_t)N * 4);
    int* partial = (int*)alloc((size_t)N * 4);
    int* row_start = (int*)alloc((size_t)N * 4);
    int* blk = (int*)alloc(256 * 4);
    float* dinv = (float*)alloc((size_t)N * 4);
    int* rank = (int*)alloc((size_t)E * 4);
    int* col_idx = (int*)alloc((size_t)E * 4);
    float* gs1 = (float*)alloc(512 * 4);
    float* gs2 = (float*)alloc(512 * 4);
    __hip_bfloat16* Wt1 = (__hip_bfloat16*)alloc(256 * 128 * 2);
    __hip_bfloat16* Wt2 = (__hip_bfloat16*)alloc(256 * 256 * 2);
    __hip_bfloat16* Wtf = (__hip_bfloat16*)alloc(256 * 256 * 2);
    // xs (N x128) + aggX (N x128) contiguous; both dead after gemm1 -> agg2 reuses.
    __hip_bfloat16* xs = (__hip_bfloat16*)alloc((size_t)N * NFEAT * 2 * 2);
    __hip_bfloat16* aggX = xs + (size_t)N * NFEAT;
    __hip_bfloat16* agg2 = xs;
    __hip_bfloat16* h1 = (__hip_bfloat16*)alloc((size_t)N * HID * 2);
    __hip_bfloat16* h2 = (__hip_bfloat16*)alloc((size_t)N * HID * 2);
    __hip_bfloat16* bufB = h1;  // bn2 out (h1 dead by then)

    hipMemsetAsync(row_cnt, 0, (size_t)N * 4, stream);
    hipMemsetAsync(gs1, 0, 1024 * 4, stream);

    // CSR build
    k_count<<<(E + 255) / 256, 256, 0, stream>>>(ei, E, row_cnt, rank);
    int nblk = (N + 255) / 256;
    k_scan1<<<nblk, 256, 0, stream>>>(row_cnt, N, partial, blk);
    k_scan2<<<1, 256, 0, stream>>>(blk, nblk);
    k_finalize<<<nblk, 256, 0, stream>>>(partial, blk, row_cnt, N, row_start, dinv);
    k_fill<<<(E + 255) / 256, 256, 0, stream>>>(ei, rank, row_start, E, col_idx);

    k_transpose3<<<640, 256, 0, stream>>>(W1, W2, Wfc, Wt1, Wt2, Wtf);

    // xs = dinv_row * x (bf16); shift = log2(128/4) = 5
    k_scale_cast<<<(N * NFEAT / 4 + 255) / 256, 256, 0, stream>>>(x, dinv, xs, 5, N * NFEAT / 4);

    dim3 gg((N + 63) / 64, 2);
    int sg = (N + 3) / 4;
    // Layer 1: aggregate (128ch) -> GEMM (+bias, fused stats)
    k_spmm_w<NFEAT><<<sg, 256, 0, stream>>>(xs, row_start, row_cnt, col_idx, dinv, aggX, N);
    k_gemm2<NFEAT><<<gg, 256, 0, stream>>>(aggX, Wt1, b1, h1, nullptr, gs1, gs1 + 256, N);
    // BN1 (+dinv pre-scale, in place) -> Layer 2 aggregate -> GEMM
    k_bnnorm<<<(N * HID / 4 + 255) / 256, 256, 0, stream>>>(h1, gs1, gs1 + 256, g1, be1, dinv,
                                                            invN, h1, N * HID / 4);
    k_spmm_w<HID><<<sg, 256, 0, stream>>>(h1, row_start, row_cnt, col_idx, dinv, agg2, N);
    k_gemm2<HID><<<gg, 256, 0, stream>>>(agg2, Wt2, b2, h2, nullptr, gs2, gs2 + 256, N);
    // BN2 -> final linear (fp32 out)
    k_bnnorm<<<(N * HID / 4 + 255) / 256, 256, 0, stream>>>(h2, gs2, gs2 + 256, g2, be2, nullptr,
                                                            invN, bufB, N * HID / 4);
    k_gemm2<HID><<<gg, 256, 0, stream>>>(bufB, Wtf, bfc, nullptr, out, nullptr, nullptr, N);
}